// Round 7
// baseline (437.561 us; speedup 1.0000x reference)
//
#include <hip/hip_runtime.h>

#define BQ 2048
#define MM 65536
#define CC 128
#define NSPLIT 32
#define KCHUNK (MM/NSPLIT)
#define NQB (BQ/64)
#define NBUCKET 1024
#define NTRI ((NQB*(NQB+1))/2)   // 528 lower-triangle cells

typedef short short8 __attribute__((ext_vector_type(8)));
typedef float f32x4 __attribute__((ext_vector_type(4)));
typedef unsigned int u32;

__device__ __forceinline__ unsigned short f2bf(float x) {
    unsigned int u = __builtin_bit_cast(unsigned int, x);
    u = (u + 0x7FFFu + ((u >> 16) & 1u)) >> 16;
    return (unsigned short)u;
}
__device__ __forceinline__ float bf2f(unsigned short u) {
    return __builtin_bit_cast(float, (unsigned int)u << 16);
}
__device__ __forceinline__ int bucket_of(float v) {
    return (int)fminf(fmaxf(v * 1024.0f, 0.0f), 1023.0f);
}

// ---------------- exact query rank by seed_time (parallel, deterministic) -------------
__global__ __launch_bounds__(256) void qrank_kernel(
    const float* __restrict__ seed, int* __restrict__ qperm,
    int* __restrict__ qrank, float* __restrict__ seed_s)
{
    int t = threadIdx.x;
    int q = blockIdx.x*8 + (t >> 5);
    int l32 = t & 31;
    float v = seed[q];
    int r = 0;
    for (int seg = 0; seg < 64; ++seg) {
        int j = seg*32 + l32;
        float u = seed[j];
        r += (u < v) || (u == v && j < q);
    }
    #pragma unroll
    for (int m2 = 1; m2 < 32; m2 <<= 1) r += __shfl_xor(r, m2, 32);
    if (l32 == 0) { qperm[r] = q; qrank[q] = r; seed_s[r] = v; }
}

// ---------------- counting sort of memory keys by mst ---------------------------------
__global__ __launch_bounds__(256) void sort_hist_kernel(
    const float* __restrict__ mst, unsigned int* __restrict__ histT)
{
    __shared__ unsigned int h[NBUCKET];
    int t = threadIdx.x, b = blockIdx.x;
    #pragma unroll
    for (int j = t; j < NBUCKET; j += 256) h[j] = 0;
    __syncthreads();
    int bin = bucket_of(mst[b*256 + t]);
    atomicAdd(&h[bin], 1u);
    __syncthreads();
    #pragma unroll
    for (int j = t; j < NBUCKET; j += 256) histT[(size_t)j*256 + b] = h[j];
}

__global__ __launch_bounds__(64) void sort_scanA_kernel(
    unsigned int* __restrict__ histT, unsigned int* __restrict__ btot)
{
    int j = blockIdx.x;
    int t = threadIdx.x;
    uint4 v = *(uint4*)(histT + (size_t)j*256 + t*4);
    unsigned int s0 = v.x, s1 = v.y, s2 = v.z, s3 = v.w;
    unsigned int tsum = s0 + s1 + s2 + s3;
    unsigned int inc = tsum;
    #pragma unroll
    for (int off = 1; off < 64; off <<= 1) {
        unsigned int n = __shfl_up(inc, off, 64);
        if (t >= off) inc += n;
    }
    unsigned int ex = inc - tsum;
    uint4 o;
    o.x = ex; o.y = ex + s0; o.z = ex + s0 + s1; o.w = ex + s0 + s1 + s2;
    *(uint4*)(histT + (size_t)j*256 + t*4) = o;
    if (t == 63) btot[j] = inc;
}

__global__ __launch_bounds__(1024) void sort_scanB_kernel(
    const unsigned int* __restrict__ btot, unsigned int* __restrict__ gbase)
{
    __shared__ unsigned int sc[NBUCKET];
    int j = threadIdx.x;
    unsigned int tot = btot[j];
    sc[j] = tot;
    __syncthreads();
    for (int off = 1; off < NBUCKET; off <<= 1) {
        unsigned int y = (j >= off) ? sc[j - off] : 0u;
        __syncthreads();
        sc[j] += y;
        __syncthreads();
    }
    gbase[j] = sc[j] - tot;
}

__global__ __launch_bounds__(256) void sort_scatter_kernel(
    const float* __restrict__ mst, const unsigned int* __restrict__ histT,
    const unsigned int* __restrict__ gbase,
    int* __restrict__ dperm, float* __restrict__ mst_s)
{
    __shared__ int bins[256];
    int t = threadIdx.x, b = blockIdx.x;
    int i = b*256 + t;
    float v = mst[i];
    int bin = bucket_of(v);
    bins[t] = bin;
    __syncthreads();
    int pos = 0;
    for (int j = 0; j < t; ++j) pos += (bins[j] == bin);
    unsigned int dest = gbase[bin] + histT[(size_t)bin*256 + b] + pos;
    dperm[dest] = i;
    mst_s[dest] = v;
}

// ---------------- memory l2norm (gathered) -> xhat + xhatT, both coalesced ------------
__global__ __launch_bounds__(256) void mem_norm_kernel(
    const float* __restrict__ mx, const int* __restrict__ dperm,
    const int* __restrict__ memy,
    unsigned short* __restrict__ xhat, unsigned short* __restrict__ xhatT,
    float* __restrict__ y_s)
{
    __shared__ __align__(16) unsigned short tile[128*132];  // bf16, stride 132
    __shared__ float rs[128];
    __shared__ float invn[128];
    __shared__ int operm[128];
    const int t = threadIdx.x;
    const int kb0 = blockIdx.x * 128;

    if (t < 128) operm[t] = dperm[kb0 + t];
    __syncthreads();
    if (t < 128) y_s[kb0 + t] = (float)memy[operm[t]];

    float4 vals[16];
    #pragma unroll
    for (int i = 0; i < 16; ++i) {
        int f4 = t + 256*i;              // 4096 float4s = 128 rows x 32
        int row = f4 >> 5, col4 = f4 & 31;
        float4 v = *(const float4*)(mx + (size_t)operm[row]*CC + col4*4);
        vals[i] = v;
        float s = v.x*v.x + v.y*v.y + v.z*v.z + v.w*v.w;
        #pragma unroll
        for (int m2 = 1; m2 < 32; m2 <<= 1) s += __shfl_xor(s, m2, 64);
        if ((t & 31) == 0) rs[row] = s;
    }
    __syncthreads();
    if (t < 128) invn[t] = 1.0f / fmaxf(sqrtf(rs[t]), 1e-12f);
    __syncthreads();
    #pragma unroll
    for (int i = 0; i < 16; ++i) {
        int f4 = t + 256*i;
        int row = f4 >> 5, col4 = f4 & 31;
        float sc = invn[row];
        float4 v = vals[i];
        ushort4 o;
        o.x = f2bf(v.x*sc); o.y = f2bf(v.y*sc); o.z = f2bf(v.z*sc); o.w = f2bf(v.w*sc);
        *(ushort4*)&tile[row*132 + col4*4] = o;
    }
    __syncthreads();
    // xhat row-major, coalesced
    #pragma unroll
    for (int i = 0; i < 8; ++i) {
        int u = t + 256*i;               // 2048 units = 128 rows x 16
        int row = u >> 4, c8 = u & 15;
        ushort4 a0 = *(ushort4*)&tile[row*132 + c8*8];
        ushort4 a1 = *(ushort4*)&tile[row*132 + c8*8 + 4];
        *(ushort4*)(xhat + (size_t)(kb0 + row)*CC + c8*8) = a0;
        *(ushort4*)(xhat + (size_t)(kb0 + row)*CC + c8*8 + 4) = a1;
    }
    // xhatT [c][m], coalesced 256B runs per c
    #pragma unroll
    for (int i = 0; i < 8; ++i) {
        int u = t + 256*i;               // 2048 units = 128 c x 16 key-octets
        int c = u >> 4, k8 = u & 15;
        ushort4 o0, o1;
        o0.x = tile[(k8*8+0)*132 + c]; o0.y = tile[(k8*8+1)*132 + c];
        o0.z = tile[(k8*8+2)*132 + c]; o0.w = tile[(k8*8+3)*132 + c];
        o1.x = tile[(k8*8+4)*132 + c]; o1.y = tile[(k8*8+5)*132 + c];
        o1.z = tile[(k8*8+6)*132 + c]; o1.w = tile[(k8*8+7)*132 + c];
        *(ushort4*)(xhatT + (size_t)c*MM + kb0 + k8*8) = o0;
        *(ushort4*)(xhatT + (size_t)c*MM + kb0 + k8*8 + 4) = o1;
    }
}

// ---------------- query prep (+ etab fold): q2 = (l2norm(f)@Kw + kb)@Kw^T * log2e -----
__global__ __launch_bounds__(256) void query_prep_kernel(
    const float* __restrict__ feat, const float* __restrict__ keyw,
    const float* __restrict__ keyb, const float* __restrict__ msgw,
    const float* __restrict__ msgb, const float* __restrict__ yemb,
    const int* __restrict__ qrank,
    unsigned short* __restrict__ q2, float* __restrict__ a,
    float* __restrict__ etab)
{
    __shared__ float fl[4][128], t1[4][128];
    const int t = threadIdx.x;
    if (blockIdx.x == BQ/4) {           // folded etab: etab = y_emb@W3 + msg_b
        if (t < 128) {
            float acc0 = msgb[t], acc1 = msgb[t];
            for (int c2 = 0; c2 < 128; ++c2) {
                float w3 = msgw[(256 + c2)*128 + t];
                acc0 = fmaf(yemb[c2], w3, acc0);
                acc1 = fmaf(yemb[128 + c2], w3, acc1);
            }
            etab[t] = acc0;
            etab[128 + t] = acc1;
        }
        return;
    }
    const int w = t >> 6;
    const int lane = t & 63;
    const int b = blockIdx.x*4 + w;
    const int j0 = lane, j1 = lane + 64;
    float f0 = feat[b*CC + j0], f1 = feat[b*CC + j1];
    fl[w][j0] = f0; fl[w][j1] = f1;
    float s = f0*f0 + f1*f1;
    #pragma unroll
    for (int m2 = 1; m2 < 64; m2 <<= 1) s += __shfl_xor(s, m2, 64);
    float invn = 1.0f / fmaxf(sqrtf(s), 1e-12f);
    __syncthreads();
    float g0 = 0.f, g1 = 0.f, a0 = 0.f, a1 = 0.f;
    for (int i = 0; i < 128; ++i) {
        float x = fl[w][i];
        g0 = fmaf(x, keyw[i*128 + j0], g0);
        g1 = fmaf(x, keyw[i*128 + j1], g1);
        a0 = fmaf(x, msgw[i*128 + j0], a0);
        a1 = fmaf(x, msgw[i*128 + j1], a1);
    }
    t1[w][j0] = g0*invn + keyb[j0];
    t1[w][j1] = g1*invn + keyb[j1];
    a[b*CC + j0] = a0;
    a[b*CC + j1] = a1;
    __syncthreads();
    float q0 = 0.f, q1 = 0.f;
    for (int c2 = 0; c2 < 128; ++c2) {
        float u = t1[w][c2];
        q0 = fmaf(u, keyw[j0*128 + c2], q0);
        q1 = fmaf(u, keyw[j1*128 + c2], q1);
    }
    const float LOG2E = 1.4426950408889634f;
    int rb = qrank[b];
    q2[rb*CC + j0] = f2bf(q0 * LOG2E);
    q2[rb*CC + j1] = f2bf(q1 * LOG2E);
}

// ---------------- flash attention: ZERO-STAGING (direct global->VGPR operands) --------
// Both MFMA B-operands are 16B-contiguous in global memory (kf from xhat rows, vf from
// xhatT rows) and the chunk working set (2 MB) is L2-resident. No K/V LDS, no barriers,
// no cross-wave coordination: waves free-run; latency hidden by TLP (~12 waves/CU).
// LDS = per-wave P buffer only (9 KB/block).
__global__ __launch_bounds__(256, 2) void attn_kernel(
    const unsigned short* __restrict__ xhat,
    const unsigned short* __restrict__ xhatT,
    const unsigned short* __restrict__ q2,
    const float* __restrict__ seed_s,
    const float* __restrict__ mst_s,
    const float* __restrict__ y_s,
    unsigned short* __restrict__ Upart,
    float* __restrict__ lpart,
    float* __restrict__ wypart)
{
    __shared__ __align__(16) unsigned short P_lds[4][16*72];

    const int tid = threadIdx.x;
    const int w = tid >> 6;
    const int lane = tid & 63;
    const int g = lane >> 4;
    const int l15 = lane & 15;

    // triangle id -> (qb, chunk): heavy (chunk<=qb) cells first
    int qb, chunk;
    {
        int id = blockIdx.x;
        if (id < NTRI) {
            int q = 0, base = 0;
            while (id >= base + q + 1) { base += q + 1; ++q; }
            qb = q; chunk = id - base;
        } else {
            int k = id - NTRI;
            int q = 0;
            while (k >= (NQB - 1) - q) { k -= (NQB - 1) - q; ++q; }
            qb = q; chunk = q + 1 + k;
        }
    }

    // ntiles: per-wave ballot (no LDS, no barrier); all waves compute the same value
    const float maxseed = seed_s[qb*64 + 63];
    int ntiles;
    {
        float tm = 3.0e38f;
        if (lane < KCHUNK/64)
            tm = (float)bucket_of(mst_s[(size_t)(chunk*(KCHUNK/64) + lane)*64]) * (1.0f/1024.0f);
        unsigned long long act = __ballot(tm <= maxseed);
        ntiles = 64 - __clzll(act);
    }
    if (ntiles == 0) return;   // no writes; final's na predicate matches exactly

    const int qrow0 = qb*64 + w*16;
    short8 qf[4];
    #pragma unroll
    for (int cs = 0; cs < 4; ++cs)
        qf[cs] = *(const short8*)(q2 + (size_t)(qrow0 + l15)*CC + cs*32 + g*8);
    float seed_r[4];
    #pragma unroll
    for (int r = 0; r < 4; ++r) seed_r[r] = seed_s[qrow0 + g*4 + r];

    f32x4 accU[8];
    #pragma unroll
    for (int n = 0; n < 8; ++n) accU[n] = (f32x4)0.f;
    float accl[4] = {0.f, 0.f, 0.f, 0.f};
    float accw[4] = {0.f, 0.f, 0.f, 0.f};

    const int cbase = chunk*KCHUNK;
    for (int kt2 = 0; kt2 < ntiles; ++kt2) {
        const int kb0 = cbase + kt2*64;

        // QK B-frags: kf[sub][cs] = xhat[key][cs*32+g*8 .. +7], key = sub*16+l15
        short8 kf[4][4];
        #pragma unroll
        for (int sub = 0; sub < 4; ++sub)
            #pragma unroll
            for (int cs = 0; cs < 4; ++cs)
                kf[sub][cs] = *(const short8*)(xhat + (size_t)(kb0 + sub*16 + l15)*CC + cs*32 + g*8);

        float mv[4], yv4[4];
        #pragma unroll
        for (int s2 = 0; s2 < 4; ++s2) {
            mv[s2]  = mst_s[kb0 + s2*16 + l15];
            yv4[s2] = y_s[kb0 + s2*16 + l15];
        }

        #pragma unroll
        for (int sub = 0; sub < 4; ++sub) {
            f32x4 s = (f32x4)0.f;
            const int key = sub*16 + l15;
            #pragma unroll
            for (int cs = 0; cs < 4; ++cs)
                s = __builtin_amdgcn_mfma_f32_16x16x32_bf16(qf[cs], kf[sub][cs], s, 0, 0, 0);
            float mstv = mv[sub];
            float yvv = yv4[sub];
            #pragma unroll
            for (int r = 0; r < 4; ++r) {
                float p = (seed_r[r] < mstv) ? 0.f : exp2f(s[r]);
                accl[r] += p;
                accw[r] += p * yvv;
                P_lds[w][(g*4 + r)*72 + key] = f2bf(p);
            }
        }

        // PV B-frags: vf[kk][n] = xhatT[c][kb0+kk*32+g*8 .. +7], c = n*16+l15
        short8 vf[2][8];
        #pragma unroll
        for (int kk = 0; kk < 2; ++kk)
            #pragma unroll
            for (int n = 0; n < 8; ++n)
                vf[kk][n] = *(const short8*)(xhatT + (size_t)(n*16 + l15)*MM + kb0 + kk*32 + g*8);

        asm volatile("s_waitcnt lgkmcnt(0)" ::: "memory");  // own-wave P writes done
        __builtin_amdgcn_sched_barrier(0);
        #pragma unroll
        for (int kk = 0; kk < 2; ++kk) {
            short8 pa = *(const short8*)((const char*)&P_lds[w][0] + l15*144 + kk*64 + g*16);
            #pragma unroll
            for (int n = 0; n < 8; ++n)
                accU[n] = __builtin_amdgcn_mfma_f32_16x16x32_bf16(pa, vf[kk][n], accU[n], 0, 0, 0);
        }
    }

    // epilogue: per-wave partial writes (16q strip each)
    const int rbase = (qb*NSPLIT + chunk)*64 + w*16;
    #pragma unroll
    for (int r = 0; r < 4; ++r) {
        float lv = accl[r], wv = accw[r];
        #pragma unroll
        for (int m2 = 1; m2 < 16; m2 <<= 1) {
            lv += __shfl_xor(lv, m2, 64);
            wv += __shfl_xor(wv, m2, 64);
        }
        if (l15 == 0) {
            lpart[rbase + g*4 + r] = lv;
            wypart[rbase + g*4 + r] = wv;
        }
    }
    #pragma unroll
    for (int n = 0; n < 8; ++n) {
        #pragma unroll
        for (int r = 0; r < 4; ++r)
            Upart[(size_t)(rbase + g*4 + r)*CC + n*16 + l15] = f2bf(accU[n][r]);
    }
}

// ---------------- fused combine + epilogue MLP ----------------------------------------
__global__ __launch_bounds__(256) void final_kernel(
    const float* __restrict__ feat, const unsigned short* __restrict__ Upart,
    const float* __restrict__ lpart, const float* __restrict__ wypart,
    const float* __restrict__ seed_s, const float* __restrict__ mst_s,
    const float* __restrict__ a, const float* __restrict__ etab,
    const float* __restrict__ msgw, const int* __restrict__ qperm,
    const float* __restrict__ uw1, const float* __restrict__ ub1,
    const float* __restrict__ uw2, const float* __restrict__ ub2,
    float* __restrict__ out)
{
    __shared__ float fl[4][128], t0[4][128], t1l[4][128];
    __shared__ int na_s;
    const int t = threadIdx.x;
    const int w = t >> 6;
    const int lane = t & 63;
    const int b0 = blockIdx.x*4;
    const int qb = b0 >> 6;
    if (t < 64) {
        float maxseed = seed_s[qb*64 + 63];
        float lb = (t < NSPLIT) ? (float)bucket_of(mst_s[(size_t)t*KCHUNK]) * (1.0f/1024.0f) : 3.0e38f;
        unsigned long long act = __ballot(lb <= maxseed);
        if (t == 0) na_s = (int)__popcll(act);
    }
    __syncthreads();
    const int na = na_s;                 // >=1 (mst_s[0] = -1e9 -> bucket 0)
    const int b = b0 + w;                // sorted row
    const int ob = qperm[b];             // original row
    const int rowin = b & 63;
    const int j0 = lane, j1 = lane + 64;
    float f0 = feat[ob*CC + j0], f1 = feat[ob*CC + j1];
    fl[w][j0] = f0; fl[w][j1] = f1;
    float lv = 0.f, wv = 0.f;
    if (lane < na) {
        int o = (qb*NSPLIT + lane)*64 + rowin;
        lv = lpart[o]; wv = wypart[o];
    }
    #pragma unroll
    for (int m2 = 1; m2 < 64; m2 <<= 1) {
        lv += __shfl_xor(lv, m2, 64);
        wv += __shfl_xor(wv, m2, 64);
    }
    float u0 = 0.f, u1 = 0.f;
    for (int j = 0; j < na; ++j) {
        const unsigned short* up = Upart + (size_t)((qb*NSPLIT + j)*64 + rowin)*CC;
        u0 += bf2f(up[j0]); u1 += bf2f(up[j1]);
    }
    t0[w][j0] = u0; t0[w][j1] = u1;
    __syncthreads();
    float linv = 1.0f / lv;
    float s1 = wv / lv;
    float acc0 = 0.f, acc1 = 0.f;
    for (int i = 0; i < 128; ++i) {
        float x = t0[w][i];
        acc0 = fmaf(x, msgw[(128 + i)*128 + j0], acc0);
        acc1 = fmaf(x, msgw[(128 + i)*128 + j1], acc1);
    }
    float mix0 = (1.f - s1)*etab[j0] + s1*etab[128 + j0];
    float mix1 = (1.f - s1)*etab[j1] + s1*etab[128 + j1];
    float hg0 = a[ob*CC + j0] + acc0*linv + mix0;
    float hg1 = a[ob*CC + j1] + acc1*linv + mix1;
    __syncthreads();
    t0[w][j0] = hg0; t0[w][j1] = hg1;
    __syncthreads();
    float h0 = ub1[j0], h1 = ub1[j1];
    for (int i = 0; i < 128; ++i) {
        float xf = fl[w][i];
        float xh = t0[w][i];
        h0 = fmaf(xf, uw1[i*128 + j0], h0);
        h1 = fmaf(xf, uw1[i*128 + j1], h1);
        h0 = fmaf(xh, uw1[(128 + i)*128 + j0], h0);
        h1 = fmaf(xh, uw1[(128 + i)*128 + j1], h1);
    }
    h0 = fmaxf(h0, 0.f); h1 = fmaxf(h1, 0.f);
    t1l[w][j0] = h0; t1l[w][j1] = h1;
    __syncthreads();
    float o0 = ub2[j0], o1 = ub2[j1];
    for (int i = 0; i < 128; ++i) {
        float x = t1l[w][i];
        o0 = fmaf(x, uw2[i*128 + j0], o0);
        o1 = fmaf(x, uw2[i*128 + j1], o1);
    }
    out[ob*CC + j0] = f0 + o0;
    out[ob*CC + j1] = f1 + o1;
}

extern "C" void kernel_launch(void* const* d_in, const int* in_sizes, int n_in,
                              void* d_out, int out_size, void* d_ws, size_t ws_size,
                              hipStream_t stream) {
    (void)in_sizes; (void)n_in; (void)out_size; (void)ws_size;
    const float* feature  = (const float*)d_in[0];
    const float* memory_x = (const float*)d_in[1];
    const int*   memory_y = (const int*)d_in[2];
    const float* seed_t   = (const float*)d_in[3];
    const float* mem_st   = (const float*)d_in[4];
    const float* key_w    = (const float*)d_in[5];
    const float* key_b    = (const float*)d_in[6];
    const float* msg_w    = (const float*)d_in[7];
    const float* msg_b    = (const float*)d_in[8];
    const float* upd_w1   = (const float*)d_in[9];
    const float* upd_b1   = (const float*)d_in[10];
    const float* upd_w2   = (const float*)d_in[11];
    const float* upd_b2   = (const float*)d_in[12];
    const float* y_emb    = (const float*)d_in[13];
    float* out = (float*)d_out;

    // ---- bump-allocated workspace (256B aligned) ----
    char* ws = (char*)d_ws;
    size_t off = 0;
    auto A = [&](size_t bytes) -> char* {
        char* p = ws + off;
        off += (bytes + 255) & ~(size_t)255;
        return p;
    };
    unsigned short* xhat  = (unsigned short*)A((size_t)MM*CC*2);        // 16 MB
    unsigned short* xhatT = (unsigned short*)A((size_t)MM*CC*2);        // 16 MB
    unsigned short* q2    = (unsigned short*)A((size_t)BQ*CC*2);        // 512 KB
    float* a      = (float*)A((size_t)BQ*CC*4);                         // 1 MB
    float* etab   = (float*)A(2*CC*4);
    float* lpart  = (float*)A((size_t)NQB*NSPLIT*64*4);                 // 256 KB
    float* wypart = (float*)A((size_t)NQB*NSPLIT*64*4);                 // 256 KB
    int*   dperm  = (int*)A((size_t)MM*4);                              // 256 KB
    float* mst_s  = (float*)A((size_t)MM*4);                            // 256 KB
    float* y_s    = (float*)A((size_t)MM*4);                            // 256 KB
    unsigned int* histT = (unsigned int*)A((size_t)NBUCKET*256*4);      // 1 MB
    unsigned int* btot  = (unsigned int*)A(NBUCKET*4);
    unsigned int* gbase = (unsigned int*)A(NBUCKET*4);
    int*   qperm  = (int*)A(BQ*4);
    int*   qrank  = (int*)A(BQ*4);
    float* seed_s = (float*)A(BQ*4);
    unsigned short* Upart = (unsigned short*)A((size_t)BQ*NSPLIT*CC*2); // 16 MB

    qrank_kernel<<<BQ/8, 256, 0, stream>>>(seed_t, qperm, qrank, seed_s);
    sort_hist_kernel<<<MM/256, 256, 0, stream>>>(mem_st, histT);
    sort_scanA_kernel<<<NBUCKET, 64, 0, stream>>>(histT, btot);
    sort_scanB_kernel<<<1, 1024, 0, stream>>>(btot, gbase);
    sort_scatter_kernel<<<MM/256, 256, 0, stream>>>(mem_st, histT, gbase, dperm, mst_s);
    mem_norm_kernel<<<MM/128, 256, 0, stream>>>(memory_x, dperm, memory_y, xhat, xhatT, y_s);
    query_prep_kernel<<<BQ/4 + 1, 256, 0, stream>>>(feature, key_w, key_b, msg_w, msg_b,
                                                    y_emb, qrank, q2, a, etab);
    attn_kernel<<<NQB*NSPLIT, 256, 0, stream>>>(xhat, xhatT, q2, seed_s, mst_s, y_s,
                                                Upart, lpart, wypart);
    final_kernel<<<BQ/4, 256, 0, stream>>>(feature, Upart, lpart, wypart, seed_s, mst_s,
                                           a, etab, msg_w, qperm,
                                           upd_w1, upd_b1, upd_w2, upd_b2, out);
}

// Round 8
// 252.062 us; speedup vs baseline: 1.7359x; 1.7359x over previous
//
#include <hip/hip_runtime.h>

#define BQ 2048
#define MM 65536
#define CC 128
#define NSPLIT 32
#define KCHUNK (MM/NSPLIT)
#define NQB (BQ/64)
#define NBUCKET 1024
#define NTRI ((NQB*(NQB+1))/2)   // 528 lower-triangle cells

typedef short short8 __attribute__((ext_vector_type(8)));
typedef float f32x4 __attribute__((ext_vector_type(4)));
typedef unsigned int u32x4 __attribute__((ext_vector_type(4)));
typedef unsigned int u32;

__device__ __forceinline__ unsigned short f2bf(float x) {
    unsigned int u = __builtin_bit_cast(unsigned int, x);
    u = (u + 0x7FFFu + ((u >> 16) & 1u)) >> 16;
    return (unsigned short)u;
}
__device__ __forceinline__ float bf2f(unsigned short u) {
    return __builtin_bit_cast(float, (unsigned int)u << 16);
}
__device__ __forceinline__ int bucket_of(float v) {
    return (int)fminf(fmaxf(v * 1024.0f, 0.0f), 1023.0f);
}
__device__ __forceinline__ u32 cvtpk(float lo, float hi) {
    u32 r;
    asm("v_cvt_pk_bf16_f32 %0, %1, %2" : "=v"(r) : "v"(lo), "v"(hi));
    return r;
}

// ---------------- exact query rank by seed_time (parallel, deterministic) -------------
__global__ __launch_bounds__(256) void qrank_kernel(
    const float* __restrict__ seed, int* __restrict__ qperm,
    int* __restrict__ qrank, float* __restrict__ seed_s)
{
    int t = threadIdx.x;
    int q = blockIdx.x*8 + (t >> 5);
    int l32 = t & 31;
    float v = seed[q];
    int r = 0;
    for (int seg = 0; seg < 64; ++seg) {
        int j = seg*32 + l32;
        float u = seed[j];
        r += (u < v) || (u == v && j < q);
    }
    #pragma unroll
    for (int m2 = 1; m2 < 32; m2 <<= 1) r += __shfl_xor(r, m2, 32);
    if (l32 == 0) { qperm[r] = q; qrank[q] = r; seed_s[r] = v; }
}

// ---------------- counting sort of memory keys by mst ---------------------------------
__global__ __launch_bounds__(256) void sort_hist_kernel(
    const float* __restrict__ mst, unsigned int* __restrict__ histT)
{
    __shared__ unsigned int h[NBUCKET];
    int t = threadIdx.x, b = blockIdx.x;
    #pragma unroll
    for (int j = t; j < NBUCKET; j += 256) h[j] = 0;
    __syncthreads();
    int bin = bucket_of(mst[b*256 + t]);
    atomicAdd(&h[bin], 1u);
    __syncthreads();
    #pragma unroll
    for (int j = t; j < NBUCKET; j += 256) histT[(size_t)j*256 + b] = h[j];
}

__global__ __launch_bounds__(64) void sort_scanA_kernel(
    unsigned int* __restrict__ histT, unsigned int* __restrict__ btot)
{
    int j = blockIdx.x;
    int t = threadIdx.x;
    uint4 v = *(uint4*)(histT + (size_t)j*256 + t*4);
    unsigned int s0 = v.x, s1 = v.y, s2 = v.z, s3 = v.w;
    unsigned int tsum = s0 + s1 + s2 + s3;
    unsigned int inc = tsum;
    #pragma unroll
    for (int off = 1; off < 64; off <<= 1) {
        unsigned int n = __shfl_up(inc, off, 64);
        if (t >= off) inc += n;
    }
    unsigned int ex = inc - tsum;
    uint4 o;
    o.x = ex; o.y = ex + s0; o.z = ex + s0 + s1; o.w = ex + s0 + s1 + s2;
    *(uint4*)(histT + (size_t)j*256 + t*4) = o;
    if (t == 63) btot[j] = inc;
}

__global__ __launch_bounds__(1024) void sort_scanB_kernel(
    const unsigned int* __restrict__ btot, unsigned int* __restrict__ gbase)
{
    __shared__ unsigned int sc[NBUCKET];
    int j = threadIdx.x;
    unsigned int tot = btot[j];
    sc[j] = tot;
    __syncthreads();
    for (int off = 1; off < NBUCKET; off <<= 1) {
        unsigned int y = (j >= off) ? sc[j - off] : 0u;
        __syncthreads();
        sc[j] += y;
        __syncthreads();
    }
    gbase[j] = sc[j] - tot;
}

__global__ __launch_bounds__(256) void sort_scatter_kernel(
    const float* __restrict__ mst, const unsigned int* __restrict__ histT,
    const unsigned int* __restrict__ gbase,
    int* __restrict__ dperm, float* __restrict__ mst_s)
{
    __shared__ int bins[256];
    int t = threadIdx.x, b = blockIdx.x;
    int i = b*256 + t;
    float v = mst[i];
    int bin = bucket_of(v);
    bins[t] = bin;
    __syncthreads();
    int pos = 0;
    for (int j = 0; j < t; ++j) pos += (bins[j] == bin);
    unsigned int dest = gbase[bin] + histT[(size_t)bin*256 + b] + pos;
    dperm[dest] = i;
    mst_s[dest] = v;
}

// ---------------- exact intra-bucket sort (value, orig idx) ---------------------------
__global__ __launch_bounds__(64) void sortfix_kernel(
    float* __restrict__ mst_s, int* __restrict__ dperm,
    const unsigned int* __restrict__ gbase, const unsigned int* __restrict__ btot)
{
    __shared__ float vals[512];
    __shared__ int idxs[512];
    int b = blockIdx.x;
    int base = (int)gbase[b];
    int n = (int)btot[b];
    if (n > 512) n = 512;              // statistically impossible (mean 64, sigma 8)
    if (n <= 1) return;
    int t = threadIdx.x;
    for (int i = t; i < n; i += 64) { vals[i] = mst_s[base + i]; idxs[i] = dperm[base + i]; }
    __syncthreads();
    for (int i = t; i < n; i += 64) {
        float v = vals[i]; int d = idxs[i];
        int rank = 0;
        for (int j = 0; j < n; ++j) {
            float vj = vals[j];
            rank += (vj < v) || (vj == v && idxs[j] < d);
        }
        mst_s[base + rank] = v;
        dperm[base + rank] = d;
    }
}

// ---------------- exact cut position per sorted query row -----------------------------
// cq[r] = #keys with mst <= seed_s[r]; allowed keys are exactly the prefix [0, cq[r]).
__global__ __launch_bounds__(256) void cq_kernel(
    const float* __restrict__ seed_s, const float* __restrict__ mst_s,
    const unsigned int* __restrict__ gbase, const unsigned int* __restrict__ btot,
    int* __restrict__ cq)
{
    int r = blockIdx.x*256 + threadIdx.x;
    float s = seed_s[r];
    int b = bucket_of(s);
    int base = (int)gbase[b];
    int n = (int)btot[b];
    int cnt = 0;
    for (int i = 0; i < n; ++i) cnt += (mst_s[base + i] <= s) ? 1 : 0;
    cq[r] = base + cnt;
}

// ---------------- memory l2norm (gathered) -> xhat + xhatT(144 rows incl y, ones) -----
__global__ __launch_bounds__(256) void mem_norm_kernel(
    const float* __restrict__ mx, const int* __restrict__ dperm,
    const int* __restrict__ memy,
    unsigned short* __restrict__ xhat, unsigned short* __restrict__ xhatT)
{
    __shared__ __align__(16) unsigned short tile[128*132];  // bf16, stride 132
    __shared__ float rs[128];
    __shared__ float invn[128];
    __shared__ int operm[128];
    const int t = threadIdx.x;
    const int kb0 = blockIdx.x * 128;

    if (t < 128) operm[t] = dperm[kb0 + t];
    __syncthreads();

    float4 vals[16];
    #pragma unroll
    for (int i = 0; i < 16; ++i) {
        int f4 = t + 256*i;              // 4096 float4s = 128 rows x 32
        int row = f4 >> 5, col4 = f4 & 31;
        float4 v = *(const float4*)(mx + (size_t)operm[row]*CC + col4*4);
        vals[i] = v;
        float s = v.x*v.x + v.y*v.y + v.z*v.z + v.w*v.w;
        #pragma unroll
        for (int m2 = 1; m2 < 32; m2 <<= 1) s += __shfl_xor(s, m2, 64);
        if ((t & 31) == 0) rs[row] = s;
    }
    __syncthreads();
    if (t < 128) invn[t] = 1.0f / fmaxf(sqrtf(rs[t]), 1e-12f);
    __syncthreads();
    #pragma unroll
    for (int i = 0; i < 16; ++i) {
        int f4 = t + 256*i;
        int row = f4 >> 5, col4 = f4 & 31;
        float sc = invn[row];
        float4 v = vals[i];
        ushort4 o;
        o.x = f2bf(v.x*sc); o.y = f2bf(v.y*sc); o.z = f2bf(v.z*sc); o.w = f2bf(v.w*sc);
        *(ushort4*)&tile[row*132 + col4*4] = o;
    }
    __syncthreads();
    // xhat row-major, coalesced
    #pragma unroll
    for (int i = 0; i < 8; ++i) {
        int u = t + 256*i;               // 2048 units = 128 rows x 16
        int row = u >> 4, c8 = u & 15;
        ushort4 a0 = *(ushort4*)&tile[row*132 + c8*8];
        ushort4 a1 = *(ushort4*)&tile[row*132 + c8*8 + 4];
        *(ushort4*)(xhat + (size_t)(kb0 + row)*CC + c8*8) = a0;
        *(ushort4*)(xhat + (size_t)(kb0 + row)*CC + c8*8 + 4) = a1;
    }
    // xhatT [c][m], coalesced 256B runs per c
    #pragma unroll
    for (int i = 0; i < 8; ++i) {
        int u = t + 256*i;               // 2048 units = 128 c x 16 key-octets
        int c = u >> 4, k8 = u & 15;
        ushort4 o0, o1;
        o0.x = tile[(k8*8+0)*132 + c]; o0.y = tile[(k8*8+1)*132 + c];
        o0.z = tile[(k8*8+2)*132 + c]; o0.w = tile[(k8*8+3)*132 + c];
        o1.x = tile[(k8*8+4)*132 + c]; o1.y = tile[(k8*8+5)*132 + c];
        o1.z = tile[(k8*8+6)*132 + c]; o1.w = tile[(k8*8+7)*132 + c];
        *(ushort4*)(xhatT + (size_t)c*MM + kb0 + k8*8) = o0;
        *(ushort4*)(xhatT + (size_t)c*MM + kb0 + k8*8 + 4) = o1;
    }
    // extended rows: 128 = y (bf16 exact), 129 = 1.0, 130..143 = 0
    if (t < 128) {
        float yv = (float)memy[operm[t]];
        xhatT[(size_t)128*MM + kb0 + t] = f2bf(yv);
        xhatT[(size_t)129*MM + kb0 + t] = 0x3F80;
        #pragma unroll
        for (int rr = 130; rr < 144; ++rr)
            xhatT[(size_t)rr*MM + kb0 + t] = 0;
    }
}

// ---------------- query prep (+ etab fold): q2 = (l2norm(f)@Kw + kb)@Kw^T * log2e -----
__global__ __launch_bounds__(256) void query_prep_kernel(
    const float* __restrict__ feat, const float* __restrict__ keyw,
    const float* __restrict__ keyb, const float* __restrict__ msgw,
    const float* __restrict__ msgb, const float* __restrict__ yemb,
    const int* __restrict__ qrank,
    unsigned short* __restrict__ q2, float* __restrict__ a,
    float* __restrict__ etab)
{
    __shared__ float fl[4][128], t1[4][128];
    const int t = threadIdx.x;
    if (blockIdx.x == BQ/4) {           // folded etab: etab = y_emb@W3 + msg_b
        if (t < 128) {
            float acc0 = msgb[t], acc1 = msgb[t];
            for (int c2 = 0; c2 < 128; ++c2) {
                float w3 = msgw[(256 + c2)*128 + t];
                acc0 = fmaf(yemb[c2], w3, acc0);
                acc1 = fmaf(yemb[128 + c2], w3, acc1);
            }
            etab[t] = acc0;
            etab[128 + t] = acc1;
        }
        return;
    }
    const int w = t >> 6;
    const int lane = t & 63;
    const int b = blockIdx.x*4 + w;
    const int j0 = lane, j1 = lane + 64;
    float f0 = feat[b*CC + j0], f1 = feat[b*CC + j1];
    fl[w][j0] = f0; fl[w][j1] = f1;
    float s = f0*f0 + f1*f1;
    #pragma unroll
    for (int m2 = 1; m2 < 64; m2 <<= 1) s += __shfl_xor(s, m2, 64);
    float invn = 1.0f / fmaxf(sqrtf(s), 1e-12f);
    __syncthreads();
    float g0 = 0.f, g1 = 0.f, a0 = 0.f, a1 = 0.f;
    for (int i = 0; i < 128; ++i) {
        float x = fl[w][i];
        g0 = fmaf(x, keyw[i*128 + j0], g0);
        g1 = fmaf(x, keyw[i*128 + j1], g1);
        a0 = fmaf(x, msgw[i*128 + j0], a0);
        a1 = fmaf(x, msgw[i*128 + j1], a1);
    }
    t1[w][j0] = g0*invn + keyb[j0];
    t1[w][j1] = g1*invn + keyb[j1];
    a[b*CC + j0] = a0;
    a[b*CC + j1] = a1;
    __syncthreads();
    float q0 = 0.f, q1 = 0.f;
    for (int c2 = 0; c2 < 128; ++c2) {
        float u = t1[w][c2];
        q0 = fmaf(u, keyw[j0*128 + c2], q0);
        q1 = fmaf(u, keyw[j1*128 + c2], q1);
    }
    const float LOG2E = 1.4426950408889634f;
    int rb = qrank[b];
    q2[rb*CC + j0] = f2bf(q0 * LOG2E);
    q2[rb*CC + j1] = f2bf(q1 * LOG2E);
}

// ---------------- flash attention: swapped MFMA, in-lane P, stats via MFMA ------------
// QK: mfma(A=K-rows, B=Q) -> S^T[key][q], q = lane&15. K rows permuted so that each
// lane's 16 S values are exactly its PV B-fragment (keys kk*32+g*8+i for its own q).
// PV: mfma(A=VT-rows(144 incl y,ones), B=P) -> U^T[c][q]; c=128 -> wy, c=129 -> l.
// Mask is an exact prefix: allowed iff key_global < cq[q]. No loads in the K-loop.
__global__ __launch_bounds__(256, 4) void attn_kernel(
    const unsigned short* __restrict__ xhat,
    const unsigned short* __restrict__ xhatT,
    const unsigned short* __restrict__ q2,
    const int* __restrict__ cq,
    unsigned short* __restrict__ Upart,
    float* __restrict__ lpart,
    float* __restrict__ wypart)
{
    __shared__ __align__(16) char pool[34816];   // K 16KB @0, VT 18KB @16384; bounce reuse

    const int tid = threadIdx.x;
    const int w = tid >> 6;
    const int lane = tid & 63;
    const int g = lane >> 4;
    const int l15 = lane & 15;

    // triangle id -> (qb, chunk): heavy (chunk<=qb) cells first
    int qb, chunk;
    {
        int id = blockIdx.x;
        if (id < NTRI) {
            int q = 0, base = 0;
            while (id >= base + q + 1) { base += q + 1; ++q; }
            qb = q; chunk = id - base;
        } else {
            int k = id - NTRI;
            int q = 0;
            while (k >= (NQB - 1) - q) { k -= (NQB - 1) - q; ++q; }
            qb = q; chunk = q + 1 + k;
        }
    }

    const int cbase = chunk*KCHUNK;
    const int cqmax = cq[qb*64 + 63];            // queries sorted: row 63 has max seed
    int ntiles = (cqmax - cbase + 63) >> 6;
    if (ntiles <= 0) return;                     // matches final's na predicate exactly
    if (ntiles > KCHUNK/64) ntiles = KCHUNK/64;

    const int qrow0 = qb*64 + w*16;
    short8 qf[4];
    #pragma unroll
    for (int cs = 0; cs < 4; ++cs)
        qf[cs] = *(const short8*)(q2 + (size_t)(qrow0 + l15)*CC + cs*32 + g*8);
    const int cqv = cq[qrow0 + l15];             // this lane's q cut (absolute key count)
    const int g8 = g*8;

    f32x4 accU[9];
    #pragma unroll
    for (int n = 0; n < 9; ++n) accU[n] = (f32x4)0.f;

    for (int kt2 = 0; kt2 < ntiles; ++kt2) {
        const int kb0 = cbase + kt2*64;
        __syncthreads();
        // stage K tile rows 0..63 (swizzle v(row) = (row&3)|((row>>3)&3)<<2)
        #pragma unroll
        for (int i = 0; i < 4; ++i) {
            int cid = tid + i*256;
            int row = cid >> 4, cc = cid & 15;
            int vr = (row & 3) | (((row >> 3) & 3) << 2);
            uint4 v = *(const uint4*)(xhat + (size_t)(kb0 + row)*CC + cc*8);
            *(uint4*)(pool + row*256 + ((cc << 4) ^ (vr << 4))) = v;
        }
        // stage VT tile rows 0..143 (swizzle by c&7)
        #pragma unroll
        for (int i = 0; i < 5; ++i) {
            int cid = tid + i*256;
            if (cid < 1152) {
                int c = cid >> 3, cc = cid & 7;
                uint4 v = *(const uint4*)(xhatT + (size_t)c*MM + kb0 + cc*8);
                *(uint4*)(pool + 16384 + c*128 + ((cc << 4) ^ ((c & 7) << 4))) = v;
            }
        }
        __syncthreads();

        const int cut = cqv - kb0;
        u32 pw[8];
        #pragma unroll
        for (int s = 0; s < 4; ++s) {
            // A-row a holds key kappa(s,a) = (s>>1)*32 + (a>>2)*8 + (s&1)*4 + (a&3)
            const int krow = ((s >> 1) << 5) + ((l15 & 12) << 1) + ((s & 1) << 2) + (l15 & 3);
            f32x4 st = (f32x4)0.f;
            #pragma unroll
            for (int cs = 0; cs < 4; ++cs) {
                short8 kfr = *(const short8*)(pool + krow*256 + ((cs*64 + g*16) ^ (l15 << 4)));
                st = __builtin_amdgcn_mfma_f32_16x16x32_bf16(kfr, qf[cs], st, 0, 0, 0);
            }
            const int kbase = ((s >> 1) << 5) + g8 + ((s & 1) << 2);
            float p0 = (kbase + 0 < cut) ? exp2f(st[0]) : 0.f;
            float p1 = (kbase + 1 < cut) ? exp2f(st[1]) : 0.f;
            float p2 = (kbase + 2 < cut) ? exp2f(st[2]) : 0.f;
            float p3 = (kbase + 3 < cut) ? exp2f(st[3]) : 0.f;
            pw[s*2]     = cvtpk(p0, p1);
            pw[s*2 + 1] = cvtpk(p2, p3);
        }
        // in-lane P fragments: pa[kk] = keys kk*32 + g*8 + {0..7} for q = l15
        u32x4 t0v = {pw[0], pw[1], pw[2], pw[3]};
        u32x4 t1v = {pw[4], pw[5], pw[6], pw[7]};
        short8 pa0 = __builtin_bit_cast(short8, t0v);
        short8 pa1 = __builtin_bit_cast(short8, t1v);

        #pragma unroll
        for (int sc = 0; sc < 9; ++sc) {
            const int vrow = sc*16 + l15;
            const char* Vr = pool + 16384 + vrow*128;
            const int swz = (vrow & 7) << 4;
            short8 vf0 = *(const short8*)(Vr + ((g*16) ^ swz));
            short8 vf1 = *(const short8*)(Vr + ((64 + g*16) ^ swz));
            accU[sc] = __builtin_amdgcn_mfma_f32_16x16x32_bf16(vf0, pa0, accU[sc], 0, 0, 0);
            accU[sc] = __builtin_amdgcn_mfma_f32_16x16x32_bf16(vf1, pa1, accU[sc], 0, 0, 0);
        }
    }

    // ---- epilogue ----
    const int rbase = (qb*NSPLIT + chunk)*64;
    // stats: c = 128 + g*4 + r -> g==0: r=0 is wy-row, r=1 is ones-row (f32 exact)
    if (g == 0) {
        wypart[rbase + w*16 + l15] = accU[8][0];
        lpart[rbase + w*16 + l15]  = accU[8][1];
    }
    __syncthreads();                     // all waves done reading pool; reuse as bounce
    char* bounce = pool + w*4352;        // per-wave 16 rows x 272B
    #pragma unroll
    for (int sc = 0; sc < 8; ++sc) {
        #pragma unroll
        for (int jp = 0; jp < 2; ++jp) {
            u32 pk = cvtpk(accU[sc][2*jp], accU[sc][2*jp + 1]);
            *(u32*)(bounce + l15*272 + (sc*16 + g*4 + 2*jp)*2) = pk;
        }
    }
    __syncthreads();
    #pragma unroll
    for (int p = 0; p < 4; ++p) {
        int seg = p*4 + (lane & 3);
        int q = lane >> 2;
        uint4 v = *(const uint4*)(bounce + q*272 + seg*16);
        *(uint4*)((char*)Upart + (size_t)(rbase + w*16 + q)*256 + seg*16) = v;
    }
}

// ---------------- fused combine + epilogue MLP ----------------------------------------
__global__ __launch_bounds__(256) void final_kernel(
    const float* __restrict__ feat, const unsigned short* __restrict__ Upart,
    const float* __restrict__ lpart, const float* __restrict__ wypart,
    const int* __restrict__ cq,
    const float* __restrict__ a, const float* __restrict__ etab,
    const float* __restrict__ msgw, const int* __restrict__ qperm,
    const float* __restrict__ uw1, const float* __restrict__ ub1,
    const float* __restrict__ uw2, const float* __restrict__ ub2,
    float* __restrict__ out)
{
    __shared__ float fl[4][128], t0[4][128], t1l[4][128];
    const int t = threadIdx.x;
    const int w = t >> 6;
    const int lane = t & 63;
    const int b0 = blockIdx.x*4;
    const int qb = b0 >> 6;
    const int cqmax = cq[qb*64 + 63];
    int na = (cqmax + KCHUNK - 1) >> 11;         // KCHUNK = 2048 = 2^11
    if (na > NSPLIT) na = NSPLIT;                // >= 1 since key 0 always allowed
    const int b = b0 + w;                // sorted row
    const int ob = qperm[b];             // original row
    const int rowin = b & 63;
    const int j0 = lane, j1 = lane + 64;
    float f0 = feat[ob*CC + j0], f1 = feat[ob*CC + j1];
    fl[w][j0] = f0; fl[w][j1] = f1;
    float lv = 0.f, wv = 0.f;
    if (lane < na) {
        int o = (qb*NSPLIT + lane)*64 + rowin;
        lv = lpart[o]; wv = wypart[o];
    }
    #pragma unroll
    for (int m2 = 1; m2 < 64; m2 <<= 1) {
        lv += __shfl_xor(lv, m2, 64);
        wv += __shfl_xor(wv, m2, 64);
    }
    float u0 = 0.f, u1 = 0.f;
    for (int j = 0; j < na; ++j) {
        const unsigned short* up = Upart + (size_t)((qb*NSPLIT + j)*64 + rowin)*CC;
        u0 += bf2f(up[j0]); u1 += bf2f(up[j1]);
    }
    t0[w][j0] = u0; t0[w][j1] = u1;
    __syncthreads();
    float linv = 1.0f / lv;
    float s1 = wv / lv;
    float acc0 = 0.f, acc1 = 0.f;
    for (int i = 0; i < 128; ++i) {
        float x = t0[w][i];
        acc0 = fmaf(x, msgw[(128 + i)*128 + j0], acc0);
        acc1 = fmaf(x, msgw[(128 + i)*128 + j1], acc1);
    }
    float mix0 = (1.f - s1)*etab[j0] + s1*etab[128 + j0];
    float mix1 = (1.f - s1)*etab[j1] + s1*etab[128 + j1];
    float hg0 = a[ob*CC + j0] + acc0*linv + mix0;
    float hg1 = a[ob*CC + j1] + acc1*linv + mix1;
    __syncthreads();
    t0[w][j0] = hg0; t0[w][j1] = hg1;
    __syncthreads();
    float h0 = ub1[j0], h1 = ub1[j1];
    for (int i = 0; i < 128; ++i) {
        float xf = fl[w][i];
        float xh = t0[w][i];
        h0 = fmaf(xf, uw1[i*128 + j0], h0);
        h1 = fmaf(xf, uw1[i*128 + j1], h1);
        h0 = fmaf(xh, uw1[(128 + i)*128 + j0], h0);
        h1 = fmaf(xh, uw1[(128 + i)*128 + j1], h1);
    }
    h0 = fmaxf(h0, 0.f); h1 = fmaxf(h1, 0.f);
    t1l[w][j0] = h0; t1l[w][j1] = h1;
    __syncthreads();
    float o0 = ub2[j0], o1 = ub2[j1];
    for (int i = 0; i < 128; ++i) {
        float x = t1l[w][i];
        o0 = fmaf(x, uw2[i*128 + j0], o0);
        o1 = fmaf(x, uw2[i*128 + j1], o1);
    }
    out[ob*CC + j0] = f0 + o0;
    out[ob*CC + j1] = f1 + o1;
}

extern "C" void kernel_launch(void* const* d_in, const int* in_sizes, int n_in,
                              void* d_out, int out_size, void* d_ws, size_t ws_size,
                              hipStream_t stream) {
    (void)in_sizes; (void)n_in; (void)out_size; (void)ws_size;
    const float* feature  = (const float*)d_in[0];
    const float* memory_x = (const float*)d_in[1];
    const int*   memory_y = (const int*)d_in[2];
    const float* seed_t   = (const float*)d_in[3];
    const float* mem_st   = (const float*)d_in[4];
    const float* key_w    = (const float*)d_in[5];
    const float* key_b    = (const float*)d_in[6];
    const float* msg_w    = (const float*)d_in[7];
    const float* msg_b    = (const float*)d_in[8];
    const float* upd_w1   = (const float*)d_in[9];
    const float* upd_b1   = (const float*)d_in[10];
    const float* upd_w2   = (const float*)d_in[11];
    const float* upd_b2   = (const float*)d_in[12];
    const float* y_emb    = (const float*)d_in[13];
    float* out = (float*)d_out;

    // ---- bump-allocated workspace (256B aligned) ----
    char* ws = (char*)d_ws;
    size_t off = 0;
    auto A = [&](size_t bytes) -> char* {
        char* p = ws + off;
        off += (bytes + 255) & ~(size_t)255;
        return p;
    };
    unsigned short* xhat  = (unsigned short*)A((size_t)MM*CC*2);         // 16 MB
    unsigned short* xhatT = (unsigned short*)A((size_t)MM*144*2);        // 18.9 MB
    unsigned short* q2    = (unsigned short*)A((size_t)BQ*CC*2);         // 512 KB
    float* a      = (float*)A((size_t)BQ*CC*4);                          // 1 MB
    float* etab   = (float*)A(2*CC*4);
    float* lpart  = (float*)A((size_t)NQB*NSPLIT*64*4);                  // 256 KB
    float* wypart = (float*)A((size_t)NQB*NSPLIT*64*4);                  // 256 KB
    int*   dperm  = (int*)A((size_t)MM*4);                               // 256 KB
    float* mst_s  = (float*)A((size_t)MM*4);                             // 256 KB
    unsigned int* btot  = (unsigned int*)A(NBUCKET*4);
    unsigned int* gbase = (unsigned int*)A(NBUCKET*4);
    int*   qperm  = (int*)A(BQ*4);
    int*   qrank  = (int*)A(BQ*4);
    float* seed_s = (float*)A(BQ*4);
    int*   cqbuf  = (int*)A(BQ*4);
    unsigned short* Upart = (unsigned short*)A((size_t)BQ*NSPLIT*CC*2);  // 16 MB
    // histT aliases Upart: consumed by sort_scatter before attn writes Upart.
    unsigned int* histT = (unsigned int*)Upart;                          // 1 MB

    qrank_kernel<<<BQ/8, 256, 0, stream>>>(seed_t, qperm, qrank, seed_s);
    sort_hist_kernel<<<MM/256, 256, 0, stream>>>(mem_st, histT);
    sort_scanA_kernel<<<NBUCKET, 64, 0, stream>>>(histT, btot);
    sort_scanB_kernel<<<1, 1024, 0, stream>>>(btot, gbase);
    sort_scatter_kernel<<<MM/256, 256, 0, stream>>>(mem_st, histT, gbase, dperm, mst_s);
    sortfix_kernel<<<NBUCKET, 64, 0, stream>>>(mst_s, dperm, gbase, btot);
    cq_kernel<<<BQ/256, 256, 0, stream>>>(seed_s, mst_s, gbase, btot, cqbuf);
    mem_norm_kernel<<<MM/128, 256, 0, stream>>>(memory_x, dperm, memory_y, xhat, xhatT);
    query_prep_kernel<<<BQ/4 + 1, 256, 0, stream>>>(feature, key_w, key_b, msg_w, msg_b,
                                                    y_emb, qrank, q2, a, etab);
    attn_kernel<<<NQB*NSPLIT, 256, 0, stream>>>(xhat, xhatT, q2, cqbuf,
                                                Upart, lpart, wypart);
    final_kernel<<<BQ/4, 256, 0, stream>>>(feature, Upart, lpart, wypart, cqbuf,
                                           a, etab, msg_w, qperm,
                                           upd_w1, upd_b1, upd_w2, upd_b2, out);
}